// Round 7
// baseline (344.639 us; speedup 1.0000x reference)
//
#include <hip/hip_runtime.h>
#include <hip/hip_bf16.h>
#include <cstdint>
#include <cstddef>

#define B_ROWS 16384
#define D_DIM  256
#define TEMP_INV 14.285714285714286f   // 1/0.07

#define BM 128
#define BN 128
#define BK 64

using frag_ab = __attribute__((ext_vector_type(8))) short;   // 8 bf16
using frag_cd = __attribute__((ext_vector_type(4))) float;   // 4 fp32

__device__ __forceinline__ void gld_lds16(const void* g, void* l) {
    __builtin_amdgcn_global_load_lds(
        (const __attribute__((address_space(1))) void*)g,
        (__attribute__((address_space(3))) void*)l,
        16, 0, 0);
}

// Kernel 1: L2-normalize q,d rows -> bf16; diag[i] = cos(q_i,d_i)/T in fp32.
// Also zero-initializes row_sums/col_sums/out (replaces memset dispatches).
__global__ __launch_bounds__(256) void norm_diag_kernel(
    const float* __restrict__ q, const float* __restrict__ d,
    __hip_bfloat16* __restrict__ qn, __hip_bfloat16* __restrict__ dn,
    float* __restrict__ diag,
    float* __restrict__ row_sums, float* __restrict__ col_sums,
    float* __restrict__ out) {
    const int b = blockIdx.x;
    if (b < 64)            row_sums[b * 256 + threadIdx.x] = 0.0f;
    else if (b < 128)      col_sums[(b - 64) * 256 + threadIdx.x] = 0.0f;
    else if (b == 128 && threadIdx.x == 0) out[0] = 0.0f;

    const int row  = b * 4 + (threadIdx.x >> 6);
    const int lane = threadIdx.x & 63;

    const float4 qv = ((const float4*)(q + (size_t)row * D_DIM))[lane];
    const float4 dv = ((const float4*)(d + (size_t)row * D_DIM))[lane];

    float qss = qv.x*qv.x + qv.y*qv.y + qv.z*qv.z + qv.w*qv.w;
    float dss = dv.x*dv.x + dv.y*dv.y + dv.z*dv.z + dv.w*dv.w;
    float qd  = qv.x*dv.x + qv.y*dv.y + qv.z*dv.z + qv.w*dv.w;
#pragma unroll
    for (int off = 32; off; off >>= 1) {
        qss += __shfl_down(qss, off);
        dss += __shfl_down(dss, off);
        qd  += __shfl_down(qd,  off);
    }
    qss = __shfl(qss, 0);
    dss = __shfl(dss, 0);
    qd  = __shfl(qd,  0);

    const float qinv = 1.0f / fmaxf(sqrtf(qss), 1e-12f);
    const float dinv = 1.0f / fmaxf(sqrtf(dss), 1e-12f);

    struct alignas(8) bf4 { __hip_bfloat16 x, y, z, w; };
    bf4 qo, doo;
    qo.x = __float2bfloat16(qv.x * qinv);
    qo.y = __float2bfloat16(qv.y * qinv);
    qo.z = __float2bfloat16(qv.z * qinv);
    qo.w = __float2bfloat16(qv.w * qinv);
    doo.x = __float2bfloat16(dv.x * dinv);
    doo.y = __float2bfloat16(dv.y * dinv);
    doo.z = __float2bfloat16(dv.z * dinv);
    doo.w = __float2bfloat16(dv.w * dinv);
    *(bf4*)(qn + (size_t)row * D_DIM + lane * 4) = qo;
    *(bf4*)(dn + (size_t)row * D_DIM + lane * 4) = doo;

    if (lane == 0) diag[row] = qd * qinv * dinv * TEMP_INV;
}

// Kernel 2: 128x128 tile of sim = qn . dn^T; fused exp(sim - 1/T) row/col sums.
// Two-barrier BK=64 K-loop (R4 skeleton), but ONLY B staged in LDS (16 KB,
// 128B-row-stride XOR swizzle — the only stride proven conflict-free R2/R3/R5).
// A fragments load global->VGPR (16B/lane contiguous in row-major qn, L1/L2-hot),
// issued BEFORE the staging barrier so its vmcnt(0) drain covers them for free.
// Halves LDS read+write traffic and halves LDS/block -> occupancy up.
// XCD-aware 1D grid swizzle (R6, small win). Butterfly all-to-all epilogue.
__global__ __launch_bounds__(256) void gemm_lse_kernel(
    const __hip_bfloat16* __restrict__ qn, const __hip_bfloat16* __restrict__ dn,
    float* __restrict__ row_sums, float* __restrict__ col_sums) {
    __shared__ __hip_bfloat16 Bs[BN][BK];   // 16 KB

    const int t    = threadIdx.x;
    const int lane = t & 63;
    const int w    = t >> 6;
    const int l15  = lane & 15;
    const int quad = lane >> 4;
    const int m0   = (w >> 1) * 64;
    const int n0   = (w & 1) * 64;

    // XCD swizzle: id -> (bx, by)
    const int id  = blockIdx.x;
    const int xcd = id & 7;
    const int j   = id >> 3;
    const int bx  = (xcd << 4) | (j & 15);
    const int by  = j >> 4;
    const int rowBase = by * BM;
    const int colBase = bx * BN;

    // B staging map: thread t -> row t/8, GLOBAL k-chunk ((t&7)^(row&7)); LDS off = t*16B
    const int rsub = t >> 3;
    const int ksub = (((t & 7) ^ (rsub & 7)) << 3);
    const __hip_bfloat16* gb = dn + (size_t)(colBase + rsub) * D_DIM + ksub;
    __hip_bfloat16* lb = &Bs[0][0] + t * 8;

    // A direct-load base: lane (l15, quad) of wave w reads row m0+mi*16+l15,
    // k = kt + kk + quad*8 (16B aligned).
    const __hip_bfloat16* gA = qn + (size_t)(rowBase + m0 + l15) * D_DIM + quad * 8;

    frag_cd acc[4][4];
#pragma unroll
    for (int i = 0; i < 4; ++i)
#pragma unroll
        for (int jj = 0; jj < 4; ++jj)
            acc[i][jj] = (frag_cd){0.0f, 0.0f, 0.0f, 0.0f};

    for (int kt = 0; kt < D_DIM; kt += BK) {
        if (kt) __syncthreads();
#pragma unroll
        for (int it = 0; it < 4; ++it)     // +32 rows: (row&7) invariant, same swizzle
            gld_lds16(gb + (size_t)it * 32 * D_DIM + kt, lb + it * 32 * BK);

        // A frags for this kt: both kk halves, issued before the barrier drain.
        frag_ab af[2][4];
#pragma unroll
        for (int kk2 = 0; kk2 < 2; ++kk2)
#pragma unroll
            for (int mi = 0; mi < 4; ++mi)
                af[kk2][mi] = *(const frag_ab*)(gA + (size_t)mi * 16 * D_DIM
                                                + kt + kk2 * 32);

        __syncthreads();   // drains vmcnt (B staging + A loads) + orders LDS

#pragma unroll
        for (int kk2 = 0; kk2 < 2; ++kk2) {
            const int c = kk2 * 4 + quad;            // logical 16B-chunk index
            frag_ab bfr[4];
#pragma unroll
            for (int i = 0; i < 4; ++i) {
                const int R = n0 + i * 16 + l15;
                bfr[i] = *(const frag_ab*)&Bs[R][(c ^ (l15 & 7)) << 3];
            }
#pragma unroll
            for (int mi = 0; mi < 4; ++mi)
#pragma unroll
                for (int ni = 0; ni < 4; ++ni)
                    acc[mi][ni] = __builtin_amdgcn_mfma_f32_16x16x32_bf16(
                        af[kk2][mi], bfr[ni], acc[mi][ni], 0, 0, 0);
        }
    }

    // ---- Epilogue ----
    // C frag layout (m89): lane holds col = n0+ni*16+l15, row = m0+mi*16+quad*4+r.
    float rv[16];
    float cv[4] = {0.0f, 0.0f, 0.0f, 0.0f};
#pragma unroll
    for (int pp = 0; pp < 16; ++pp) rv[pp] = 0.0f;
#pragma unroll
    for (int mi = 0; mi < 4; ++mi)
#pragma unroll
        for (int ni = 0; ni < 4; ++ni)
#pragma unroll
            for (int r = 0; r < 4; ++r) {
                const float e = __expf((acc[mi][ni][r] - 1.0f) * TEMP_INV);
                rv[mi * 4 + r] += e;
                cv[ni] += e;
            }

    // Row butterfly all-reduce over the 16 lanes of each quad; end: rv[0] <-> p = l15.
#pragma unroll
    for (int s = 0; s < 4; ++s) {
        const bool b = (l15 >> s) & 1;
#pragma unroll
        for (int i = 0; i < (8 >> s); ++i) {
            const float a0 = rv[2 * i], a1 = rv[2 * i + 1];
            const float keep = b ? a1 : a0;
            const float send = b ? a0 : a1;
            rv[i] = keep + __shfl_xor(send, 1 << s);
        }
    }
    atomicAdd(&row_sums[rowBase + m0 + (l15 >> 2) * 16 + quad * 4 + (l15 & 3)], rv[0]);

    // Col butterfly all-reduce over the 4 quads; end: cv[0] <-> ni = quad.
#pragma unroll
    for (int s = 0; s < 2; ++s) {
        const bool b = (quad >> s) & 1;
#pragma unroll
        for (int i = 0; i < (2 >> s); ++i) {
            const float a0 = cv[2 * i], a1 = cv[2 * i + 1];
            const float keep = b ? a1 : a0;
            const float send = b ? a0 : a1;
            cv[i] = keep + __shfl_xor(send, 16 << s);
        }
    }
    atomicAdd(&col_sums[colBase + n0 + quad * 16 + l15], cv[0]);
}

// Kernel 3 (parallel): each block reduces 256 rows, atomicAdd into zeroed out[0].
__global__ __launch_bounds__(256) void finalize_kernel(
    const float* __restrict__ rs, const float* __restrict__ cs,
    const float* __restrict__ dg, float* __restrict__ out) {
    const int i = blockIdx.x * 256 + threadIdx.x;
    float s = logf(rs[i]) + logf(cs[i]) - 2.0f * dg[i];
#pragma unroll
    for (int off = 32; off; off >>= 1) s += __shfl_down(s, off);
    __shared__ float buf[4];
    if ((threadIdx.x & 63) == 0) buf[threadIdx.x >> 6] = s;
    __syncthreads();
    if (threadIdx.x == 0) {
        float tot = (buf[0] + buf[1] + buf[2] + buf[3]) / (2.0f * B_ROWS);
        if (blockIdx.x == 0) tot += TEMP_INV;   // undo the fixed exp shift
        atomicAdd(out, tot);
    }
}

extern "C" void kernel_launch(void* const* d_in, const int* in_sizes, int n_in,
                              void* d_out, int out_size, void* d_ws, size_t ws_size,
                              hipStream_t stream) {
    const float* q = (const float*)d_in[0];
    const float* d = (const float*)d_in[1];
    float* out = (float*)d_out;

    char* ws = (char*)d_ws;
    __hip_bfloat16* qn = (__hip_bfloat16*)ws;                       // 8 MB
    __hip_bfloat16* dn = qn + (size_t)B_ROWS * D_DIM;               // 8 MB
    float* row_sums = (float*)(ws + 2 * (size_t)B_ROWS * D_DIM * sizeof(__hip_bfloat16));
    float* col_sums = row_sums + B_ROWS;
    float* diag     = col_sums + B_ROWS;

    norm_diag_kernel<<<B_ROWS / 4, 256, 0, stream>>>(q, d, qn, dn, diag,
                                                     row_sums, col_sums, out);
    gemm_lse_kernel<<<(B_ROWS / BM) * (B_ROWS / BN), 256, 0, stream>>>(qn, dn, row_sums, col_sums);
    finalize_kernel<<<B_ROWS / 256, 256, 0, stream>>>(row_sums, col_sums, diag, out);
}

// Round 8
// 213.893 us; speedup vs baseline: 1.6113x; 1.6113x over previous
//
#include <hip/hip_runtime.h>
#include <hip/hip_bf16.h>
#include <cstdint>
#include <cstddef>

#define B_ROWS 16384
#define D_DIM  256
#define TEMP_INV 14.285714285714286f   // 1/0.07

#define BM 128
#define BN 128
#define BK 128   // fp8 elems per K-tile -> 128 B LDS row stride (proven conflict-free)

using frag_cd = __attribute__((ext_vector_type(4))) float;   // 4 fp32

__device__ __forceinline__ void gld_lds16(const void* g, void* l) {
    __builtin_amdgcn_global_load_lds(
        (const __attribute__((address_space(1))) void*)g,
        (__attribute__((address_space(3))) void*)l,
        16, 0, 0);
}

// Kernel 1: L2-normalize q,d rows -> fp8 e4m3 (HW cvt_pk, RNE); diag[i] exact fp32.
// Also zero-initializes row_sums/col_sums/out (replaces memset dispatches).
__global__ __launch_bounds__(256) void norm_diag_kernel(
    const float* __restrict__ q, const float* __restrict__ d,
    unsigned int* __restrict__ qn, unsigned int* __restrict__ dn,
    float* __restrict__ diag,
    float* __restrict__ row_sums, float* __restrict__ col_sums,
    float* __restrict__ out) {
    const int b = blockIdx.x;
    if (b < 64)            row_sums[b * 256 + threadIdx.x] = 0.0f;
    else if (b < 128)      col_sums[(b - 64) * 256 + threadIdx.x] = 0.0f;
    else if (b == 128 && threadIdx.x == 0) out[0] = 0.0f;

    const int row  = b * 4 + (threadIdx.x >> 6);
    const int lane = threadIdx.x & 63;

    const float4 qv = ((const float4*)(q + (size_t)row * D_DIM))[lane];
    const float4 dv = ((const float4*)(d + (size_t)row * D_DIM))[lane];

    float qss = qv.x*qv.x + qv.y*qv.y + qv.z*qv.z + qv.w*qv.w;
    float dss = dv.x*dv.x + dv.y*dv.y + dv.z*dv.z + dv.w*dv.w;
    float qd  = qv.x*dv.x + qv.y*dv.y + qv.z*dv.z + qv.w*dv.w;
#pragma unroll
    for (int off = 32; off; off >>= 1) {
        qss += __shfl_down(qss, off);
        dss += __shfl_down(dss, off);
        qd  += __shfl_down(qd,  off);
    }
    qss = __shfl(qss, 0);
    dss = __shfl(dss, 0);
    qd  = __shfl(qd,  0);

    const float qinv = 1.0f / fmaxf(sqrtf(qss), 1e-12f);
    const float dinv = 1.0f / fmaxf(sqrtf(dss), 1e-12f);

    // Pack 4 normalized values -> 4 fp8 e4m3 bytes (OCP, HW round-nearest-even).
    int qp = 0, dp = 0;
    qp = __builtin_amdgcn_cvt_pk_fp8_f32(qv.x * qinv, qv.y * qinv, qp, false);
    qp = __builtin_amdgcn_cvt_pk_fp8_f32(qv.z * qinv, qv.w * qinv, qp, true);
    dp = __builtin_amdgcn_cvt_pk_fp8_f32(dv.x * dinv, dv.y * dinv, dp, false);
    dp = __builtin_amdgcn_cvt_pk_fp8_f32(dv.z * dinv, dv.w * dinv, dp, true);
    qn[row * (D_DIM / 4) + lane] = (unsigned int)qp;
    dn[row * (D_DIM / 4) + lane] = (unsigned int)dp;

    if (lane == 0) diag[row] = qd * qinv * dinv * TEMP_INV;
}

// Kernel 2: 128x128 tile of sim = qn . dn^T in fp8 e4m3; fused exp(sim - 1/T) sums.
// R6 two-barrier skeleton, but fp8 halves all bytes: LDS rows are 128 fp8 = 128 B
// stride (the only stride proven conflict-free: R2 vs R3/R5). BK=128 -> K=256 in
// 2 stages -> 3 barriers/block. XOR swizzle on 16B chunks: phys chunk p of row r
// holds logical p^(r&7); gld_lds staging keeps wave-uniform-base + lane*16.
// Frag reads are ds_read_b64 (8 fp8/lane, k = quad*8..+8). XCD-aware 1D grid
// swizzle (R6). Butterfly all-to-all epilogue reduce (R4).
__global__ __launch_bounds__(256) void gemm_lse_kernel(
    const unsigned char* __restrict__ qn, const unsigned char* __restrict__ dn,
    float* __restrict__ row_sums, float* __restrict__ col_sums) {
    __shared__ unsigned char As[BM][BK];   // 16 KB
    __shared__ unsigned char Bs[BN][BK];   // 16 KB

    const int t    = threadIdx.x;
    const int lane = t & 63;
    const int w    = t >> 6;
    const int l15  = lane & 15;
    const int quad = lane >> 4;
    const int m0   = (w >> 1) * 64;
    const int n0   = (w & 1) * 64;

    // XCD swizzle: id -> (bx, by)
    const int id  = blockIdx.x;
    const int xcd = id & 7;
    const int j   = id >> 3;
    const int bx  = (xcd << 4) | (j & 15);
    const int by  = j >> 4;
    const int rowBase = by * BM;
    const int colBase = bx * BN;

    // staging: thread t -> row t/8 (+32/issue), phys 16B chunk p=t&7,
    // GLOBAL logical chunk g = p^(row&7); LDS offset = t*16.
    const int rsub = t >> 3;
    const int g    = ((t & 7) ^ (rsub & 7)) << 4;   // byte offset of logical chunk
    const unsigned char* ga = qn + (size_t)(rowBase + rsub) * D_DIM + g;
    const unsigned char* gb = dn + (size_t)(colBase + rsub) * D_DIM + g;
    unsigned char* la = &As[0][0] + t * 16;
    unsigned char* lb = &Bs[0][0] + t * 16;

    frag_cd acc[4][4];
#pragma unroll
    for (int i = 0; i < 4; ++i)
#pragma unroll
        for (int jj = 0; jj < 4; ++jj)
            acc[i][jj] = (frag_cd){0.0f, 0.0f, 0.0f, 0.0f};

    for (int kt = 0; kt < D_DIM; kt += BK) {
        if (kt) __syncthreads();
#pragma unroll
        for (int it = 0; it < 4; ++it) {   // +32 rows/issue: row&7 invariant
            gld_lds16(ga + (size_t)it * 32 * D_DIM + kt, la + it * 32 * BK);
            gld_lds16(gb + (size_t)it * 32 * D_DIM + kt, lb + it * 32 * BK);
        }
        __syncthreads();   // drains vmcnt (gld_lds) + orders LDS

#pragma unroll
        for (int ks = 0; ks < 4; ++ks) {
            // lane's 8 fp8: k-bytes [ks*32 + quad*8, +8). 16B chunk C, half h.
            const int C = ks * 2 + (quad >> 1);
            const int h = (quad & 1) * 8;
            long af[4], bfr[4];
#pragma unroll
            for (int i = 0; i < 4; ++i) {
                const int R  = m0 + i * 16 + l15;
                const int PC = C ^ (l15 & 7);
                af[i] = *(const long*)&As[R][PC * 16 + h];
            }
#pragma unroll
            for (int i = 0; i < 4; ++i) {
                const int R  = n0 + i * 16 + l15;
                const int PC = C ^ (l15 & 7);
                bfr[i] = *(const long*)&Bs[R][PC * 16 + h];
            }
#pragma unroll
            for (int mi = 0; mi < 4; ++mi)
#pragma unroll
                for (int ni = 0; ni < 4; ++ni)
                    acc[mi][ni] = __builtin_amdgcn_mfma_f32_16x16x32_fp8_fp8(
                        af[mi], bfr[ni], acc[mi][ni], 0, 0, 0);
        }
    }

    // ---- Epilogue ----
    // C frag layout (shape-determined, dtype-independent — m89/m121):
    // lane holds col = n0+ni*16+l15, row = m0+mi*16+quad*4+r.
    float rv[16];
    float cv[4] = {0.0f, 0.0f, 0.0f, 0.0f};
#pragma unroll
    for (int pp = 0; pp < 16; ++pp) rv[pp] = 0.0f;
#pragma unroll
    for (int mi = 0; mi < 4; ++mi)
#pragma unroll
        for (int ni = 0; ni < 4; ++ni)
#pragma unroll
            for (int r = 0; r < 4; ++r) {
                const float e = __expf((acc[mi][ni][r] - 1.0f) * TEMP_INV);
                rv[mi * 4 + r] += e;
                cv[ni] += e;
            }

    // Row butterfly all-reduce over the 16 lanes of each quad; end: rv[0] <-> p = l15.
#pragma unroll
    for (int s = 0; s < 4; ++s) {
        const bool b = (l15 >> s) & 1;
#pragma unroll
        for (int i = 0; i < (8 >> s); ++i) {
            const float a0 = rv[2 * i], a1 = rv[2 * i + 1];
            const float keep = b ? a1 : a0;
            const float send = b ? a0 : a1;
            rv[i] = keep + __shfl_xor(send, 1 << s);
        }
    }
    atomicAdd(&row_sums[rowBase + m0 + (l15 >> 2) * 16 + quad * 4 + (l15 & 3)], rv[0]);

    // Col butterfly all-reduce over the 4 quads; end: cv[0] <-> ni = quad.
#pragma unroll
    for (int s = 0; s < 2; ++s) {
        const bool b = (quad >> s) & 1;
#pragma unroll
        for (int i = 0; i < (2 >> s); ++i) {
            const float a0 = cv[2 * i], a1 = cv[2 * i + 1];
            const float keep = b ? a1 : a0;
            const float send = b ? a0 : a1;
            cv[i] = keep + __shfl_xor(send, 16 << s);
        }
    }
    atomicAdd(&col_sums[colBase + n0 + quad * 16 + l15], cv[0]);
}

// Kernel 3 (parallel): each block reduces 256 rows, atomicAdd into zeroed out[0].
__global__ __launch_bounds__(256) void finalize_kernel(
    const float* __restrict__ rs, const float* __restrict__ cs,
    const float* __restrict__ dg, float* __restrict__ out) {
    const int i = blockIdx.x * 256 + threadIdx.x;
    float s = logf(rs[i]) + logf(cs[i]) - 2.0f * dg[i];
#pragma unroll
    for (int off = 32; off; off >>= 1) s += __shfl_down(s, off);
    __shared__ float buf[4];
    if ((threadIdx.x & 63) == 0) buf[threadIdx.x >> 6] = s;
    __syncthreads();
    if (threadIdx.x == 0) {
        float tot = (buf[0] + buf[1] + buf[2] + buf[3]) / (2.0f * B_ROWS);
        if (blockIdx.x == 0) tot += TEMP_INV;   // undo the fixed exp shift
        atomicAdd(out, tot);
    }
}

extern "C" void kernel_launch(void* const* d_in, const int* in_sizes, int n_in,
                              void* d_out, int out_size, void* d_ws, size_t ws_size,
                              hipStream_t stream) {
    const float* q = (const float*)d_in[0];
    const float* d = (const float*)d_in[1];
    float* out = (float*)d_out;

    char* ws = (char*)d_ws;
    unsigned char* qn = (unsigned char*)ws;                         // 4 MB fp8
    unsigned char* dn = qn + (size_t)B_ROWS * D_DIM;                // 4 MB fp8
    float* row_sums = (float*)(ws + 2 * (size_t)B_ROWS * D_DIM);
    float* col_sums = row_sums + B_ROWS;
    float* diag     = col_sums + B_ROWS;

    norm_diag_kernel<<<B_ROWS / 4, 256, 0, stream>>>(
        q, d, (unsigned int*)qn, (unsigned int*)dn, diag, row_sums, col_sums, out);
    gemm_lse_kernel<<<(B_ROWS / BM) * (B_ROWS / BN), 256, 0, stream>>>(
        qn, dn, row_sums, col_sums);
    finalize_kernel<<<B_ROWS / 256, 256, 0, stream>>>(row_sums, col_sums, diag, out);
}

// Round 9
// 205.642 us; speedup vs baseline: 1.6759x; 1.0401x over previous
//
#include <hip/hip_runtime.h>
#include <hip/hip_bf16.h>
#include <cstdint>
#include <cstddef>

#define B_ROWS 16384
#define D_DIM  256
#define TEMP_INV 14.285714285714286f   // 1/0.07

#define BM 128
#define BN 128
#define BK 128   // fp8 elems per K-tile -> 128 B LDS row stride (proven conflict-free)

using frag_cd = __attribute__((ext_vector_type(4))) float;   // 4 fp32
using long2v  = __attribute__((ext_vector_type(2))) long;    // one 16B LDS chunk

__device__ __forceinline__ void gld_lds16(const void* g, void* l) {
    __builtin_amdgcn_global_load_lds(
        (const __attribute__((address_space(1))) void*)g,
        (__attribute__((address_space(3))) void*)l,
        16, 0, 0);
}

// Kernel 1: L2-normalize q,d rows -> fp8 e4m3 (HW cvt_pk, RNE); diag[i] exact fp32.
// Also zero-initializes row_sums/col_sums/out (replaces memset dispatches).
__global__ __launch_bounds__(256) void norm_diag_kernel(
    const float* __restrict__ q, const float* __restrict__ d,
    unsigned int* __restrict__ qn, unsigned int* __restrict__ dn,
    float* __restrict__ diag,
    float* __restrict__ row_sums, float* __restrict__ col_sums,
    float* __restrict__ out) {
    const int b = blockIdx.x;
    if (b < 64)            row_sums[b * 256 + threadIdx.x] = 0.0f;
    else if (b < 128)      col_sums[(b - 64) * 256 + threadIdx.x] = 0.0f;
    else if (b == 128 && threadIdx.x == 0) out[0] = 0.0f;

    const int row  = b * 4 + (threadIdx.x >> 6);
    const int lane = threadIdx.x & 63;

    const float4 qv = ((const float4*)(q + (size_t)row * D_DIM))[lane];
    const float4 dv = ((const float4*)(d + (size_t)row * D_DIM))[lane];

    float qss = qv.x*qv.x + qv.y*qv.y + qv.z*qv.z + qv.w*qv.w;
    float dss = dv.x*dv.x + dv.y*dv.y + dv.z*dv.z + dv.w*dv.w;
    float qd  = qv.x*dv.x + qv.y*dv.y + qv.z*dv.z + qv.w*dv.w;
#pragma unroll
    for (int off = 32; off; off >>= 1) {
        qss += __shfl_down(qss, off);
        dss += __shfl_down(dss, off);
        qd  += __shfl_down(qd,  off);
    }
    qss = __shfl(qss, 0);
    dss = __shfl(dss, 0);
    qd  = __shfl(qd,  0);

    const float qinv = 1.0f / fmaxf(sqrtf(qss), 1e-12f);
    const float dinv = 1.0f / fmaxf(sqrtf(dss), 1e-12f);

    // Pack 4 normalized values -> 4 fp8 e4m3 bytes (OCP, HW round-nearest-even).
    int qp = 0, dp = 0;
    qp = __builtin_amdgcn_cvt_pk_fp8_f32(qv.x * qinv, qv.y * qinv, qp, false);
    qp = __builtin_amdgcn_cvt_pk_fp8_f32(qv.z * qinv, qv.w * qinv, qp, true);
    dp = __builtin_amdgcn_cvt_pk_fp8_f32(dv.x * dinv, dv.y * dinv, dp, false);
    dp = __builtin_amdgcn_cvt_pk_fp8_f32(dv.z * dinv, dv.w * dinv, dp, true);
    qn[row * (D_DIM / 4) + lane] = (unsigned int)qp;
    dn[row * (D_DIM / 4) + lane] = (unsigned int)dp;

    if (lane == 0) diag[row] = qd * qinv * dinv * TEMP_INV;
}

// Kernel 2: 128x128 tile of sim = qn . dn^T in fp8 e4m3; fused exp(sim - 1/T) sums.
// R8 skeleton (BK=128 fp8, 128B rows, 16B-chunk XOR swizzle, 3 barriers/block) with
// a K-GROUP REPARTITION: quad q owns whole chunks {q, q+4} per stage; MFMA step
// 2cs consumes the chunk's low 8B, step 2cs+1 the high 8B. One ds_read_b128 per
// frag per chunk-set (half the LDS read instrs of R8's b64 scheme) and the bank
// pattern matches the proven-conflict-free bf16 b128 pattern (R2/R4/R6: 8 lanes
// per 4-bank group, 2-way per phase = free). Valid because A and B place the same
// global k in the same (quad,j) MFMA slot — dot-product order within a K-group is
// arbitrary. XCD-aware 1D grid swizzle (R6). Butterfly all-to-all epilogue (R4).
__global__ __launch_bounds__(256) void gemm_lse_kernel(
    const unsigned char* __restrict__ qn, const unsigned char* __restrict__ dn,
    float* __restrict__ row_sums, float* __restrict__ col_sums) {
    __shared__ unsigned char As[BM][BK];   // 16 KB
    __shared__ unsigned char Bs[BN][BK];   // 16 KB

    const int t    = threadIdx.x;
    const int lane = t & 63;
    const int w    = t >> 6;
    const int l15  = lane & 15;
    const int quad = lane >> 4;
    const int m0   = (w >> 1) * 64;
    const int n0   = (w & 1) * 64;

    // XCD swizzle: id -> (bx, by)
    const int id  = blockIdx.x;
    const int xcd = id & 7;
    const int j   = id >> 3;
    const int bx  = (xcd << 4) | (j & 15);
    const int by  = j >> 4;
    const int rowBase = by * BM;
    const int colBase = bx * BN;

    // staging: thread t -> row t/8 (+32/issue), phys 16B chunk p=t&7,
    // GLOBAL logical chunk g = p^(row&7); LDS offset = t*16.
    const int rsub = t >> 3;
    const int g    = ((t & 7) ^ (rsub & 7)) << 4;   // byte offset of logical chunk
    const unsigned char* ga = qn + (size_t)(rowBase + rsub) * D_DIM + g;
    const unsigned char* gb = dn + (size_t)(colBase + rsub) * D_DIM + g;
    unsigned char* la = &As[0][0] + t * 16;
    unsigned char* lb = &Bs[0][0] + t * 16;

    frag_cd acc[4][4];
#pragma unroll
    for (int i = 0; i < 4; ++i)
#pragma unroll
        for (int jj = 0; jj < 4; ++jj)
            acc[i][jj] = (frag_cd){0.0f, 0.0f, 0.0f, 0.0f};

    for (int kt = 0; kt < D_DIM; kt += BK) {
        if (kt) __syncthreads();
#pragma unroll
        for (int it = 0; it < 4; ++it) {   // +32 rows/issue: row&7 invariant
            gld_lds16(ga + (size_t)it * 32 * D_DIM + kt, la + it * 32 * BK);
            gld_lds16(gb + (size_t)it * 32 * D_DIM + kt, lb + it * 32 * BK);
        }
        __syncthreads();   // drains vmcnt (gld_lds) + orders LDS

#pragma unroll
        for (int cs = 0; cs < 2; ++cs) {
            // quad's chunk this set: C = quad + cs*4; swizzled PC = C ^ (l15&7)
            const int PC = (quad + cs * 4) ^ (l15 & 7);
            long2v a2[4], b2[4];
#pragma unroll
            for (int i = 0; i < 4; ++i)
                a2[i] = *(const long2v*)&As[m0 + i * 16 + l15][PC * 16];
#pragma unroll
            for (int i = 0; i < 4; ++i)
                b2[i] = *(const long2v*)&Bs[n0 + i * 16 + l15][PC * 16];
            // step 2*cs: low 8B of the chunk
#pragma unroll
            for (int mi = 0; mi < 4; ++mi)
#pragma unroll
                for (int ni = 0; ni < 4; ++ni)
                    acc[mi][ni] = __builtin_amdgcn_mfma_f32_16x16x32_fp8_fp8(
                        a2[mi].x, b2[ni].x, acc[mi][ni], 0, 0, 0);
            // step 2*cs+1: high 8B
#pragma unroll
            for (int mi = 0; mi < 4; ++mi)
#pragma unroll
                for (int ni = 0; ni < 4; ++ni)
                    acc[mi][ni] = __builtin_amdgcn_mfma_f32_16x16x32_fp8_fp8(
                        a2[mi].y, b2[ni].y, acc[mi][ni], 0, 0, 0);
        }
    }

    // ---- Epilogue ----
    // C frag layout (shape-determined, dtype-independent — m89/m121):
    // lane holds col = n0+ni*16+l15, row = m0+mi*16+quad*4+r.
    float rv[16];
    float cv[4] = {0.0f, 0.0f, 0.0f, 0.0f};
#pragma unroll
    for (int pp = 0; pp < 16; ++pp) rv[pp] = 0.0f;
#pragma unroll
    for (int mi = 0; mi < 4; ++mi)
#pragma unroll
        for (int ni = 0; ni < 4; ++ni)
#pragma unroll
            for (int r = 0; r < 4; ++r) {
                const float e = __expf((acc[mi][ni][r] - 1.0f) * TEMP_INV);
                rv[mi * 4 + r] += e;
                cv[ni] += e;
            }

    // Row butterfly all-reduce over the 16 lanes of each quad; end: rv[0] <-> p = l15.
#pragma unroll
    for (int s = 0; s < 4; ++s) {
        const bool b = (l15 >> s) & 1;
#pragma unroll
        for (int i = 0; i < (8 >> s); ++i) {
            const float a0 = rv[2 * i], a1 = rv[2 * i + 1];
            const float keep = b ? a1 : a0;
            const float send = b ? a0 : a1;
            rv[i] = keep + __shfl_xor(send, 1 << s);
        }
    }
    atomicAdd(&row_sums[rowBase + m0 + (l15 >> 2) * 16 + quad * 4 + (l15 & 3)], rv[0]);

    // Col butterfly all-reduce over the 4 quads; end: cv[0] <-> ni = quad.
#pragma unroll
    for (int s = 0; s < 2; ++s) {
        const bool b = (quad >> s) & 1;
#pragma unroll
        for (int i = 0; i < (2 >> s); ++i) {
            const float a0 = cv[2 * i], a1 = cv[2 * i + 1];
            const float keep = b ? a1 : a0;
            const float send = b ? a0 : a1;
            cv[i] = keep + __shfl_xor(send, 16 << s);
        }
    }
    atomicAdd(&col_sums[colBase + n0 + quad * 16 + l15], cv[0]);
}

// Kernel 3 (parallel): each block reduces 256 rows, atomicAdd into zeroed out[0].
__global__ __launch_bounds__(256) void finalize_kernel(
    const float* __restrict__ rs, const float* __restrict__ cs,
    const float* __restrict__ dg, float* __restrict__ out) {
    const int i = blockIdx.x * 256 + threadIdx.x;
    float s = logf(rs[i]) + logf(cs[i]) - 2.0f * dg[i];
#pragma unroll
    for (int off = 32; off; off >>= 1) s += __shfl_down(s, off);
    __shared__ float buf[4];
    if ((threadIdx.x & 63) == 0) buf[threadIdx.x >> 6] = s;
    __syncthreads();
    if (threadIdx.x == 0) {
        float tot = (buf[0] + buf[1] + buf[2] + buf[3]) / (2.0f * B_ROWS);
        if (blockIdx.x == 0) tot += TEMP_INV;   // undo the fixed exp shift
        atomicAdd(out, tot);
    }
}

extern "C" void kernel_launch(void* const* d_in, const int* in_sizes, int n_in,
                              void* d_out, int out_size, void* d_ws, size_t ws_size,
                              hipStream_t stream) {
    const float* q = (const float*)d_in[0];
    const float* d = (const float*)d_in[1];
    float* out = (float*)d_out;

    char* ws = (char*)d_ws;
    unsigned char* qn = (unsigned char*)ws;                         // 4 MB fp8
    unsigned char* dn = qn + (size_t)B_ROWS * D_DIM;                // 4 MB fp8
    float* row_sums = (float*)(ws + 2 * (size_t)B_ROWS * D_DIM);
    float* col_sums = row_sums + B_ROWS;
    float* diag     = col_sums + B_ROWS;

    norm_diag_kernel<<<B_ROWS / 4, 256, 0, stream>>>(
        q, d, (unsigned int*)qn, (unsigned int*)dn, diag, row_sums, col_sums, out);
    gemm_lse_kernel<<<(B_ROWS / BM) * (B_ROWS / BN), 256, 0, stream>>>(
        qn, dn, row_sums, col_sums);
    finalize_kernel<<<B_ROWS / 256, 256, 0, stream>>>(row_sums, col_sums, diag, out);
}

// Round 10
// 204.307 us; speedup vs baseline: 1.6869x; 1.0065x over previous
//
#include <hip/hip_runtime.h>
#include <hip/hip_bf16.h>
#include <cstdint>
#include <cstddef>

#define B_ROWS 16384
#define D_DIM  256
#define TEMP_INV 14.285714285714286f   // 1/0.07

#define BM 128
#define BN 128
#define BK 128   // fp8 elems per K-tile -> 128 B LDS row stride (proven conflict-free)

using frag_cd = __attribute__((ext_vector_type(4))) float;   // 4 fp32
using i32x4   = __attribute__((ext_vector_type(4))) int;     // one 16B LDS chunk
using i32x8   = __attribute__((ext_vector_type(8))) int;     // 32B f8f6f4 operand

__device__ __forceinline__ void gld_lds16(const void* g, void* l) {
    __builtin_amdgcn_global_load_lds(
        (const __attribute__((address_space(1))) void*)g,
        (__attribute__((address_space(3))) void*)l,
        16, 0, 0);
}

// Kernel 1: L2-normalize q,d rows -> fp8 e4m3 (HW cvt_pk, RNE); diag[i] exact fp32.
// Also zero-initializes row_sums/col_sums/out (replaces memset dispatches).
__global__ __launch_bounds__(256) void norm_diag_kernel(
    const float* __restrict__ q, const float* __restrict__ d,
    unsigned int* __restrict__ qn, unsigned int* __restrict__ dn,
    float* __restrict__ diag,
    float* __restrict__ row_sums, float* __restrict__ col_sums,
    float* __restrict__ out) {
    const int b = blockIdx.x;
    if (b < 64)            row_sums[b * 256 + threadIdx.x] = 0.0f;
    else if (b < 128)      col_sums[(b - 64) * 256 + threadIdx.x] = 0.0f;
    else if (b == 128 && threadIdx.x == 0) out[0] = 0.0f;

    const int row  = b * 4 + (threadIdx.x >> 6);
    const int lane = threadIdx.x & 63;

    const float4 qv = ((const float4*)(q + (size_t)row * D_DIM))[lane];
    const float4 dv = ((const float4*)(d + (size_t)row * D_DIM))[lane];

    float qss = qv.x*qv.x + qv.y*qv.y + qv.z*qv.z + qv.w*qv.w;
    float dss = dv.x*dv.x + dv.y*dv.y + dv.z*dv.z + dv.w*dv.w;
    float qd  = qv.x*dv.x + qv.y*dv.y + qv.z*dv.z + qv.w*dv.w;
#pragma unroll
    for (int off = 32; off; off >>= 1) {
        qss += __shfl_down(qss, off);
        dss += __shfl_down(dss, off);
        qd  += __shfl_down(qd,  off);
    }
    qss = __shfl(qss, 0);
    dss = __shfl(dss, 0);
    qd  = __shfl(qd,  0);

    const float qinv = 1.0f / fmaxf(sqrtf(qss), 1e-12f);
    const float dinv = 1.0f / fmaxf(sqrtf(dss), 1e-12f);

    // Pack 4 normalized values -> 4 fp8 e4m3 bytes (OCP, HW round-nearest-even).
    int qp = 0, dp = 0;
    qp = __builtin_amdgcn_cvt_pk_fp8_f32(qv.x * qinv, qv.y * qinv, qp, false);
    qp = __builtin_amdgcn_cvt_pk_fp8_f32(qv.z * qinv, qv.w * qinv, qp, true);
    dp = __builtin_amdgcn_cvt_pk_fp8_f32(dv.x * dinv, dv.y * dinv, dp, false);
    dp = __builtin_amdgcn_cvt_pk_fp8_f32(dv.z * dinv, dv.w * dinv, dp, true);
    qn[row * (D_DIM / 4) + lane] = (unsigned int)qp;
    dn[row * (D_DIM / 4) + lane] = (unsigned int)dp;

    if (lane == 0) diag[row] = qd * qinv * dinv * TEMP_INV;
}

// Kernel 2: 128x128 tile of sim = qn . dn^T in fp8 e4m3; fused exp(sim - 1/T) sums.
// R9 skeleton (BK=128 fp8, 128B rows, 16B-chunk XOR swizzle, 3 barriers/block,
// XCD grid swizzle, butterfly epilogue) with the MFMA swapped to the MX-scaled
// mfma_scale_f32_16x16x128_f8f6f4 at UNIT scales (E8M0 0x7F = 1.0 -> exact fp8
// GEMM). One MFMA per frag-pair per 128-deep stage: 32 MFMA instrs/wave vs 128 —
// frees issue slots on the saturated SIMDs (VALUBusy+MfmaUtil ~99% in R9; m148
// precedent: same swap gave +64% on the m97-skeleton ladder).
// Operand: lane (l15,quad) holds A row m0+i*16+l15, k-bytes [quad*32,+32) =
// logical chunks {2q,2q+1} -> two ds_read_b128 at PC, PC^1 (same count and same
// 8-lanes-per-chunk-slot bank pattern R9 measured conflict-free). A/B use
// identical k-indexing so any intra-reg k-permutation cancels in the dot product.
__global__ __launch_bounds__(256) void gemm_lse_kernel(
    const unsigned char* __restrict__ qn, const unsigned char* __restrict__ dn,
    float* __restrict__ row_sums, float* __restrict__ col_sums) {
    __shared__ unsigned char As[BM][BK];   // 16 KB
    __shared__ unsigned char Bs[BN][BK];   // 16 KB

    const int t    = threadIdx.x;
    const int lane = t & 63;
    const int w    = t >> 6;
    const int l15  = lane & 15;
    const int quad = lane >> 4;
    const int m0   = (w >> 1) * 64;
    const int n0   = (w & 1) * 64;

    // XCD swizzle: id -> (bx, by)
    const int id  = blockIdx.x;
    const int xcd = id & 7;
    const int j   = id >> 3;
    const int bx  = (xcd << 4) | (j & 15);
    const int by  = j >> 4;
    const int rowBase = by * BM;
    const int colBase = bx * BN;

    // staging: thread t -> row t/8 (+32/issue), phys 16B chunk p=t&7,
    // GLOBAL logical chunk g = p^(row&7); LDS offset = t*16.
    const int rsub = t >> 3;
    const int g    = ((t & 7) ^ (rsub & 7)) << 4;   // byte offset of logical chunk
    const unsigned char* ga = qn + (size_t)(rowBase + rsub) * D_DIM + g;
    const unsigned char* gb = dn + (size_t)(colBase + rsub) * D_DIM + g;
    unsigned char* la = &As[0][0] + t * 16;
    unsigned char* lb = &Bs[0][0] + t * 16;

    frag_cd acc[4][4];
#pragma unroll
    for (int i = 0; i < 4; ++i)
#pragma unroll
        for (int jj = 0; jj < 4; ++jj)
            acc[i][jj] = (frag_cd){0.0f, 0.0f, 0.0f, 0.0f};

    // quad's two swizzled chunks this lane reads (even/odd logical pair 2q, 2q+1)
    const int PC0 = (2 * quad) ^ (l15 & 7);   // second chunk is PC0 ^ 1

    for (int kt = 0; kt < D_DIM; kt += BK) {
        if (kt) __syncthreads();
#pragma unroll
        for (int it = 0; it < 4; ++it) {   // +32 rows/issue: row&7 invariant
            gld_lds16(ga + (size_t)it * 32 * D_DIM + kt, la + it * 32 * BK);
            gld_lds16(gb + (size_t)it * 32 * D_DIM + kt, lb + it * 32 * BK);
        }
        __syncthreads();   // drains vmcnt (gld_lds) + orders LDS

        i32x8 a8[4], b8[4];
#pragma unroll
        for (int i = 0; i < 4; ++i) {
            const unsigned char* rA = &As[m0 + i * 16 + l15][0];
            const i32x4 lo = *(const i32x4*)(rA + PC0 * 16);
            const i32x4 hi = *(const i32x4*)(rA + (PC0 ^ 1) * 16);
            a8[i] = __builtin_shufflevector(lo, hi, 0, 1, 2, 3, 4, 5, 6, 7);
        }
#pragma unroll
        for (int i = 0; i < 4; ++i) {
            const unsigned char* rB = &Bs[n0 + i * 16 + l15][0];
            const i32x4 lo = *(const i32x4*)(rB + PC0 * 16);
            const i32x4 hi = *(const i32x4*)(rB + (PC0 ^ 1) * 16);
            b8[i] = __builtin_shufflevector(lo, hi, 0, 1, 2, 3, 4, 5, 6, 7);
        }
#pragma unroll
        for (int mi = 0; mi < 4; ++mi)
#pragma unroll
            for (int ni = 0; ni < 4; ++ni)
                acc[mi][ni] = __builtin_amdgcn_mfma_scale_f32_16x16x128_f8f6f4(
                    a8[mi], b8[ni], acc[mi][ni],
                    0, 0,                      // cbsz=FP8 e4m3, blgp=FP8 e4m3
                    0, 0x7F7F7F7F,             // opsel_a, scale_a = 1.0 per block
                    0, 0x7F7F7F7F);            // opsel_b, scale_b = 1.0 per block
    }

    // ---- Epilogue ----
    // C frag layout (shape-determined, dtype/instr-independent — m89/m127/m128):
    // lane holds col = n0+ni*16+l15, row = m0+mi*16+quad*4+r.
    float rv[16];
    float cv[4] = {0.0f, 0.0f, 0.0f, 0.0f};
#pragma unroll
    for (int pp = 0; pp < 16; ++pp) rv[pp] = 0.0f;
#pragma unroll
    for (int mi = 0; mi < 4; ++mi)
#pragma unroll
        for (int ni = 0; ni < 4; ++ni)
#pragma unroll
            for (int r = 0; r < 4; ++r) {
                const float e = __expf((acc[mi][ni][r] - 1.0f) * TEMP_INV);
                rv[mi * 4 + r] += e;
                cv[ni] += e;
            }

    // Row butterfly all-reduce over the 16 lanes of each quad; end: rv[0] <-> p = l15.
#pragma unroll
    for (int s = 0; s < 4; ++s) {
        const bool b = (l15 >> s) & 1;
#pragma unroll
        for (int i = 0; i < (8 >> s); ++i) {
            const float a0 = rv[2 * i], a1 = rv[2 * i + 1];
            const float keep = b ? a1 : a0;
            const float send = b ? a0 : a1;
            rv[i] = keep + __shfl_xor(send, 1 << s);
        }
    }
    atomicAdd(&row_sums[rowBase + m0 + (l15 >> 2) * 16 + quad * 4 + (l15 & 3)], rv[0]);

    // Col butterfly all-reduce over the 4 quads; end: cv[0] <-> ni = quad.
#pragma unroll
    for (int s = 0; s < 2; ++s) {
        const bool b = (quad >> s) & 1;
#pragma unroll
        for (int i = 0; i < (2 >> s); ++i) {
            const float a0 = cv[2 * i], a1 = cv[2 * i + 1];
            const float keep = b ? a1 : a0;
            const float send = b ? a0 : a1;
            cv[i] = keep + __shfl_xor(send, 16 << s);
        }
    }
    atomicAdd(&col_sums[colBase + n0 + quad * 16 + l15], cv[0]);
}

// Kernel 3 (parallel): each block reduces 256 rows, atomicAdd into zeroed out[0].
__global__ __launch_bounds__(256) void finalize_kernel(
    const float* __restrict__ rs, const float* __restrict__ cs,
    const float* __restrict__ dg, float* __restrict__ out) {
    const int i = blockIdx.x * 256 + threadIdx.x;
    float s = logf(rs[i]) + logf(cs[i]) - 2.0f * dg[i];
#pragma unroll
    for (int off = 32; off; off >>= 1) s += __shfl_down(s, off);
    __shared__ float buf[4];
    if ((threadIdx.x & 63) == 0) buf[threadIdx.x >> 6] = s;
    __syncthreads();
    if (threadIdx.x == 0) {
        float tot = (buf[0] + buf[1] + buf[2] + buf[3]) / (2.0f * B_ROWS);
        if (blockIdx.x == 0) tot += TEMP_INV;   // undo the fixed exp shift
        atomicAdd(out, tot);
    }
}

extern "C" void kernel_launch(void* const* d_in, const int* in_sizes, int n_in,
                              void* d_out, int out_size, void* d_ws, size_t ws_size,
                              hipStream_t stream) {
    const float* q = (const float*)d_in[0];
    const float* d = (const float*)d_in[1];
    float* out = (float*)d_out;

    char* ws = (char*)d_ws;
    unsigned char* qn = (unsigned char*)ws;                         // 4 MB fp8
    unsigned char* dn = qn + (size_t)B_ROWS * D_DIM;                // 4 MB fp8
    float* row_sums = (float*)(ws + 2 * (size_t)B_ROWS * D_DIM);
    float* col_sums = row_sums + B_ROWS;
    float* diag     = col_sums + B_ROWS;

    norm_diag_kernel<<<B_ROWS / 4, 256, 0, stream>>>(
        q, d, (unsigned int*)qn, (unsigned int*)dn, diag, row_sums, col_sums, out);
    gemm_lse_kernel<<<(B_ROWS / BM) * (B_ROWS / BN), 256, 0, stream>>>(
        qn, dn, row_sums, col_sums);
    finalize_kernel<<<B_ROWS / 256, 256, 0, stream>>>(row_sums, col_sums, diag, out);
}

// Round 11
// 202.634 us; speedup vs baseline: 1.7008x; 1.0083x over previous
//
#include <hip/hip_runtime.h>
#include <hip/hip_bf16.h>
#include <cstdint>
#include <cstddef>

#define B_ROWS 16384
#define D_DIM  256
#define TEMP_INV 14.285714285714286f   // 1/0.07

#define BM 128
#define BN 128
#define BK 128   // fp8 elems per K-tile -> 128 B LDS row stride (proven conflict-free)

using frag_cd = __attribute__((ext_vector_type(4))) float;   // 4 fp32
using i32x4   = __attribute__((ext_vector_type(4))) int;     // one 16B LDS chunk
using i32x8   = __attribute__((ext_vector_type(8))) int;     // 32B f8f6f4 operand

__device__ __forceinline__ void gld_lds16(const void* g, void* l) {
    __builtin_amdgcn_global_load_lds(
        (const __attribute__((address_space(1))) void*)g,
        (__attribute__((address_space(3))) void*)l,
        16, 0, 0);
}

// Kernel 1: L2-normalize q,d rows -> fp8 e4m3 (HW cvt_pk, RNE); diag[i] exact fp32.
// Also zero-initializes row_sums/col_sums/out (replaces memset dispatches).
__global__ __launch_bounds__(256) void norm_diag_kernel(
    const float* __restrict__ q, const float* __restrict__ d,
    unsigned int* __restrict__ qn, unsigned int* __restrict__ dn,
    float* __restrict__ diag,
    float* __restrict__ row_sums, float* __restrict__ col_sums,
    float* __restrict__ out) {
    const int b = blockIdx.x;
    if (b < 64)            row_sums[b * 256 + threadIdx.x] = 0.0f;
    else if (b < 128)      col_sums[(b - 64) * 256 + threadIdx.x] = 0.0f;
    else if (b == 128 && threadIdx.x == 0) out[0] = 0.0f;

    const int row  = b * 4 + (threadIdx.x >> 6);
    const int lane = threadIdx.x & 63;

    const float4 qv = ((const float4*)(q + (size_t)row * D_DIM))[lane];
    const float4 dv = ((const float4*)(d + (size_t)row * D_DIM))[lane];

    float qss = qv.x*qv.x + qv.y*qv.y + qv.z*qv.z + qv.w*qv.w;
    float dss = dv.x*dv.x + dv.y*dv.y + dv.z*dv.z + dv.w*dv.w;
    float qd  = qv.x*dv.x + qv.y*dv.y + qv.z*dv.z + qv.w*dv.w;
#pragma unroll
    for (int off = 32; off; off >>= 1) {
        qss += __shfl_down(qss, off);
        dss += __shfl_down(dss, off);
        qd  += __shfl_down(qd,  off);
    }
    qss = __shfl(qss, 0);
    dss = __shfl(dss, 0);
    qd  = __shfl(qd,  0);

    const float qinv = 1.0f / fmaxf(sqrtf(qss), 1e-12f);
    const float dinv = 1.0f / fmaxf(sqrtf(dss), 1e-12f);

    // Pack 4 normalized values -> 4 fp8 e4m3 bytes (OCP, HW round-nearest-even).
    int qp = 0, dp = 0;
    qp = __builtin_amdgcn_cvt_pk_fp8_f32(qv.x * qinv, qv.y * qinv, qp, false);
    qp = __builtin_amdgcn_cvt_pk_fp8_f32(qv.z * qinv, qv.w * qinv, qp, true);
    dp = __builtin_amdgcn_cvt_pk_fp8_f32(dv.x * dinv, dv.y * dinv, dp, false);
    dp = __builtin_amdgcn_cvt_pk_fp8_f32(dv.z * dinv, dv.w * dinv, dp, true);
    qn[row * (D_DIM / 4) + lane] = (unsigned int)qp;
    dn[row * (D_DIM / 4) + lane] = (unsigned int)dp;

    if (lane == 0) diag[row] = qd * qinv * dinv * TEMP_INV;
}

// Kernel 2: 128x128 tile of sim = qn . dn^T in fp8 e4m3; fused exp(sim - 1/T) sums.
// R9 skeleton (BK=128 fp8, 128B rows, 16B-chunk XOR swizzle, 3 barriers/block,
// XCD grid swizzle, butterfly epilogue) + MX-scaled mfma_scale_f32_16x16x128_f8f6f4
// at UNIT scales (E8M0 0x7F = 1.0 -> exact fp8 GEMM), 32 MFMA instrs/wave vs 128.
// K-REPAIRING (R10 post-mortem): quad q owns logical chunks {q, q+4} (operand low
// 16B = chunk q, high 16B = chunk q+4). The two ds_read_b128 hit PC = q^(l15&7)
// and PC^4 — byte-identical per-instruction address patterns to R9's cs=0/cs=1
// reads, which measured ZERO conflicts (R10's {2q,2q+1} pairing paid 4 cyc/instr;
// the simple chunk->bank model does not predict this — trust the measurement).
// Valid because A and B use the same k-slot bijection -> dot product unchanged.
__global__ __launch_bounds__(256) void gemm_lse_kernel(
    const unsigned char* __restrict__ qn, const unsigned char* __restrict__ dn,
    float* __restrict__ row_sums, float* __restrict__ col_sums) {
    __shared__ unsigned char As[BM][BK];   // 16 KB
    __shared__ unsigned char Bs[BN][BK];   // 16 KB

    const int t    = threadIdx.x;
    const int lane = t & 63;
    const int w    = t >> 6;
    const int l15  = lane & 15;
    const int quad = lane >> 4;
    const int m0   = (w >> 1) * 64;
    const int n0   = (w & 1) * 64;

    // XCD swizzle: id -> (bx, by)
    const int id  = blockIdx.x;
    const int xcd = id & 7;
    const int j   = id >> 3;
    const int bx  = (xcd << 4) | (j & 15);
    const int by  = j >> 4;
    const int rowBase = by * BM;
    const int colBase = bx * BN;

    // staging: thread t -> row t/8 (+32/issue), phys 16B chunk p=t&7,
    // GLOBAL logical chunk g = p^(row&7); LDS offset = t*16.
    const int rsub = t >> 3;
    const int g    = ((t & 7) ^ (rsub & 7)) << 4;   // byte offset of logical chunk
    const unsigned char* ga = qn + (size_t)(rowBase + rsub) * D_DIM + g;
    const unsigned char* gb = dn + (size_t)(colBase + rsub) * D_DIM + g;
    unsigned char* la = &As[0][0] + t * 16;
    unsigned char* lb = &Bs[0][0] + t * 16;

    frag_cd acc[4][4];
#pragma unroll
    for (int i = 0; i < 4; ++i)
#pragma unroll
        for (int jj = 0; jj < 4; ++jj)
            acc[i][jj] = (frag_cd){0.0f, 0.0f, 0.0f, 0.0f};

    // quad's two swizzled chunks (logical pair {q, q+4}): PCa and PCa^4.
    const int PCa = quad ^ (l15 & 7);

    for (int kt = 0; kt < D_DIM; kt += BK) {
        if (kt) __syncthreads();
#pragma unroll
        for (int it = 0; it < 4; ++it) {   // +32 rows/issue: row&7 invariant
            gld_lds16(ga + (size_t)it * 32 * D_DIM + kt, la + it * 32 * BK);
            gld_lds16(gb + (size_t)it * 32 * D_DIM + kt, lb + it * 32 * BK);
        }
        __syncthreads();   // drains vmcnt (gld_lds) + orders LDS

        i32x8 a8[4], b8[4];
#pragma unroll
        for (int i = 0; i < 4; ++i) {
            const unsigned char* rA = &As[m0 + i * 16 + l15][0];
            const i32x4 lo = *(const i32x4*)(rA + PCa * 16);
            const i32x4 hi = *(const i32x4*)(rA + (PCa ^ 4) * 16);
            a8[i] = __builtin_shufflevector(lo, hi, 0, 1, 2, 3, 4, 5, 6, 7);
        }
#pragma unroll
        for (int i = 0; i < 4; ++i) {
            const unsigned char* rB = &Bs[n0 + i * 16 + l15][0];
            const i32x4 lo = *(const i32x4*)(rB + PCa * 16);
            const i32x4 hi = *(const i32x4*)(rB + (PCa ^ 4) * 16);
            b8[i] = __builtin_shufflevector(lo, hi, 0, 1, 2, 3, 4, 5, 6, 7);
        }
#pragma unroll
        for (int mi = 0; mi < 4; ++mi)
#pragma unroll
            for (int ni = 0; ni < 4; ++ni)
                acc[mi][ni] = __builtin_amdgcn_mfma_scale_f32_16x16x128_f8f6f4(
                    a8[mi], b8[ni], acc[mi][ni],
                    0, 0,                      // cbsz=FP8 e4m3, blgp=FP8 e4m3
                    0, 0x7F7F7F7F,             // opsel_a, scale_a = 1.0 per block
                    0, 0x7F7F7F7F);            // opsel_b, scale_b = 1.0 per block
    }

    // ---- Epilogue ----
    // C frag layout (shape-determined, dtype/instr-independent — m89/m127/m128):
    // lane holds col = n0+ni*16+l15, row = m0+mi*16+quad*4+r.
    float rv[16];
    float cv[4] = {0.0f, 0.0f, 0.0f, 0.0f};
#pragma unroll
    for (int pp = 0; pp < 16; ++pp) rv[pp] = 0.0f;
#pragma unroll
    for (int mi = 0; mi < 4; ++mi)
#pragma unroll
        for (int ni = 0; ni < 4; ++ni)
#pragma unroll
            for (int r = 0; r < 4; ++r) {
                const float e = __expf((acc[mi][ni][r] - 1.0f) * TEMP_INV);
                rv[mi * 4 + r] += e;
                cv[ni] += e;
            }

    // Row butterfly all-reduce over the 16 lanes of each quad; end: rv[0] <-> p = l15.
#pragma unroll
    for (int s = 0; s < 4; ++s) {
        const bool b = (l15 >> s) & 1;
#pragma unroll
        for (int i = 0; i < (8 >> s); ++i) {
            const float a0 = rv[2 * i], a1 = rv[2 * i + 1];
            const float keep = b ? a1 : a0;
            const float send = b ? a0 : a1;
            rv[i] = keep + __shfl_xor(send, 1 << s);
        }
    }
    atomicAdd(&row_sums[rowBase + m0 + (l15 >> 2) * 16 + quad * 4 + (l15 & 3)], rv[0]);

    // Col butterfly all-reduce over the 4 quads; end: cv[0] <-> ni = quad.
#pragma unroll
    for (int s = 0; s < 2; ++s) {
        const bool b = (quad >> s) & 1;
#pragma unroll
        for (int i = 0; i < (2 >> s); ++i) {
            const float a0 = cv[2 * i], a1 = cv[2 * i + 1];
            const float keep = b ? a1 : a0;
            const float send = b ? a0 : a1;
            cv[i] = keep + __shfl_xor(send, 16 << s);
        }
    }
    atomicAdd(&col_sums[colBase + n0 + quad * 16 + l15], cv[0]);
}

// Kernel 3 (parallel): each block reduces 256 rows, atomicAdd into zeroed out[0].
__global__ __launch_bounds__(256) void finalize_kernel(
    const float* __restrict__ rs, const float* __restrict__ cs,
    const float* __restrict__ dg, float* __restrict__ out) {
    const int i = blockIdx.x * 256 + threadIdx.x;
    float s = logf(rs[i]) + logf(cs[i]) - 2.0f * dg[i];
#pragma unroll
    for (int off = 32; off; off >>= 1) s += __shfl_down(s, off);
    __shared__ float buf[4];
    if ((threadIdx.x & 63) == 0) buf[threadIdx.x >> 6] = s;
    __syncthreads();
    if (threadIdx.x == 0) {
        float tot = (buf[0] + buf[1] + buf[2] + buf[3]) / (2.0f * B_ROWS);
        if (blockIdx.x == 0) tot += TEMP_INV;   // undo the fixed exp shift
        atomicAdd(out, tot);
    }
}

extern "C" void kernel_launch(void* const* d_in, const int* in_sizes, int n_in,
                              void* d_out, int out_size, void* d_ws, size_t ws_size,
                              hipStream_t stream) {
    const float* q = (const float*)d_in[0];
    const float* d = (const float*)d_in[1];
    float* out = (float*)d_out;

    char* ws = (char*)d_ws;
    unsigned char* qn = (unsigned char*)ws;                         // 4 MB fp8
    unsigned char* dn = qn + (size_t)B_ROWS * D_DIM;                // 4 MB fp8
    float* row_sums = (float*)(ws + 2 * (size_t)B_ROWS * D_DIM);
    float* col_sums = row_sums + B_ROWS;
    float* diag     = col_sums + B_ROWS;

    norm_diag_kernel<<<B_ROWS / 4, 256, 0, stream>>>(
        q, d, (unsigned int*)qn, (unsigned int*)dn, diag, row_sums, col_sums, out);
    gemm_lse_kernel<<<(B_ROWS / BM) * (B_ROWS / BN), 256, 0, stream>>>(
        qn, dn, row_sums, col_sums);
    finalize_kernel<<<B_ROWS / 256, 256, 0, stream>>>(row_sums, col_sums, diag, out);
}